// Round 3
// baseline (1740.005 us; speedup 1.0000x reference)
//
#include <hip/hip_runtime.h>

// Problem dims (fixed by setup_inputs): B=2, T=4096, H=16, Dk=Dv=128.
#define B_N   2
#define T_LEN 4096
#define H_N   16
#define D_K   128
#define D_V   128
#define COLS  16   // columns handled per block
#define LPC   32   // lanes per column
#define EPT   4    // state elements per thread = D_K / LPC
#define PF    4    // prefetch ring depth (steps ahead)

// ---- DPP helper: add lane-permuted copy. bound_ctrl=1 -> OOB reads give 0.
template <int CTRL>
__device__ __forceinline__ float dpp_add(float x) {
  int y = __builtin_amdgcn_update_dpp(0, __float_as_int(x), CTRL, 0xF, 0xF, true);
  return x + __int_as_float(y);
}

// Sum over a 32-lane group, result broadcast to all 32 lanes.
__device__ __forceinline__ float red32(float x) {
  x = dpp_add<0xB1>(x);   // quad_perm xor 1
  x = dpp_add<0x4E>(x);   // quad_perm xor 2
  x = dpp_add<0x124>(x);  // row_ror:4
  x = dpp_add<0x128>(x);  // row_ror:8  -> full 16-lane row sum in every lane
  // xor-16 across the two rows of this 32-lane group (LDS crossbar, no mem)
  int y = __builtin_amdgcn_ds_swizzle(__float_as_int(x), 0x401F);
  return x + __int_as_float(y);
}

struct Buf {
  float4 kk, qq;
  float vv, aa, bb;
};

__device__ __forceinline__ void ldbuf(Buf& Bu, const float* __restrict__ kp,
                                      const float* __restrict__ qp,
                                      const float* __restrict__ vp,
                                      const float* __restrict__ ap,
                                      const float* __restrict__ bp, int t) {
  Bu.kk = *(const float4*)(kp + (size_t)t * (H_N * D_K));
  Bu.qq = *(const float4*)(qp + (size_t)t * (H_N * D_K));
  Bu.vv = vp[(size_t)t * (H_N * D_V)];
  Bu.aa = ap[(size_t)t * H_N];
  Bu.bb = bp[(size_t)t * H_N];
}

__device__ __forceinline__ void stepc(const Buf& Bu, float s[EPT], int li,
                                      float* __restrict__ op) {
  float kk[4] = {Bu.kk.x, Bu.kk.y, Bu.kk.z, Bu.kk.w};
  float qq[4] = {Bu.qq.x, Bu.qq.y, Bu.qq.z, Bu.qq.w};
  // Three independent dots (2 accumulators each -> dep depth 2).
  float pk0 = fmaf(kk[0], s[0], 0.f), pk1 = fmaf(kk[1], s[1], 0.f);
  float pu0 = fmaf(qq[0], s[0], 0.f), pu1 = fmaf(qq[1], s[1], 0.f);
  float pg0 = fmaf(kk[0], qq[0], 0.f), pg1 = fmaf(kk[1], qq[1], 0.f);
  pk0 = fmaf(kk[2], s[2], pk0);  pk1 = fmaf(kk[3], s[3], pk1);
  pu0 = fmaf(qq[2], s[2], pu0);  pu1 = fmaf(qq[3], s[3], pu1);
  pg0 = fmaf(kk[2], qq[2], pg0); pg1 = fmaf(kk[3], qq[3], pg1);
  float pk = red32(pk0 + pk1);
  float pu = red32(pu0 + pu1);
  float pg = red32(pg0 + pg1);
  // S_new[:,v] = a*S[:,v] + k * tmp,  tmp = b*(v - a*(k.S[:,v]))
  float tmp = Bu.bb * (Bu.vv - Bu.aa * pk);
#pragma unroll
  for (int j = 0; j < EPT; ++j) s[j] = fmaf(Bu.aa, s[j], kk[j] * tmp);
  // o[v] = q . S_new[:,v] = a*(q.S_old) + (k.q)*tmp
  if (li == 0) *op = fmaf(pg, tmp, Bu.aa * pu);
}

extern "C" __global__ void __launch_bounds__(512, 2) gdn_kernel(
    const float* __restrict__ q, const float* __restrict__ k,
    const float* __restrict__ v, const float* __restrict__ al,
    const float* __restrict__ be, const float* __restrict__ S0,
    float* __restrict__ out) {
  // XCD-affinity decode: the 8 column-group blocks of one (b,h) share
  // (blockIdx mod 8) -> same XCD under round-robin dispatch -> k/q re-reads
  // hit that XCD's L2.
  const int bid = blockIdx.x;
  const int bh = bid & 31;   // (b,h) combo
  const int g = bid >> 5;    // column group 0..7
  const int b = bh >> 4;
  const int h = bh & 15;
  const int tid = threadIdx.x;
  const int cl = tid >> 5;   // column within group (0..15)
  const int li = tid & 31;   // lane within column (32-lane group)
  const int col = g * COLS + cl;
  const int d0 = li * EPT;

  const size_t bh_qk = ((size_t)b * T_LEN * H_N + h) * (size_t)D_K;
  const size_t bh_v = ((size_t)b * T_LEN * H_N + h) * (size_t)D_V;
  const size_t bh_ab = (size_t)b * T_LEN * H_N + h;

  const float* kp = k + bh_qk + d0;
  const float* qp = q + bh_qk + d0;
  const float* vp = v + bh_v + col;
  const float* ap = al + bh_ab;
  const float* bp = be + bh_ab;
  float* op = out + bh_v + col;
  float* sf = out + (size_t)B_N * T_LEN * H_N * D_V +
              ((size_t)(b * H_N + h) * D_K + d0) * (size_t)D_V + col;

  // initial state: s[j] = S0[b,h,d0+j,col]
  float s[EPT];
  const float* s0p = S0 + ((size_t)(b * H_N + h) * D_K + d0) * (size_t)D_V + col;
#pragma unroll
  for (int j = 0; j < EPT; ++j) s[j] = s0p[(size_t)j * D_V];

  Buf buf[PF];
#pragma unroll
  for (int i = 0; i < PF; ++i) ldbuf(buf[i], kp, qp, vp, ap, bp, i);

  for (int t = 0; t < T_LEN; t += PF) {
#pragma unroll
    for (int i = 0; i < PF; ++i) {
      stepc(buf[i], s, li, op + (size_t)(t + i) * (H_N * D_V));
      const int tn = t + i + PF;
      if (tn < T_LEN) ldbuf(buf[i], kp, qp, vp, ap, bp, tn);
    }
  }

  // final state: S_final[b,h,d,col]
#pragma unroll
  for (int j = 0; j < EPT; ++j) sf[(size_t)j * D_V] = s[j];
}

extern "C" void kernel_launch(void* const* d_in, const int* in_sizes, int n_in,
                              void* d_out, int out_size, void* d_ws,
                              size_t ws_size, hipStream_t stream) {
  const float* q = (const float*)d_in[0];
  const float* k = (const float*)d_in[1];
  const float* v = (const float*)d_in[2];
  const float* al = (const float*)d_in[3];
  const float* be = (const float*)d_in[4];
  const float* S0 = (const float*)d_in[5];
  float* out = (float*)d_out;

  dim3 grid(B_N * H_N * (D_V / COLS));  // 256 blocks
  dim3 block(COLS * LPC);               // 512 threads = 8 waves
  gdn_kernel<<<grid, block, 0, stream>>>(q, k, v, al, be, S0, out);
}

// Round 5
// 774.966 us; speedup vs baseline: 2.2453x; 2.2453x over previous
//
#include <hip/hip_runtime.h>

// Problem dims (fixed by setup_inputs): B=2, T=4096, H=16, Dk=Dv=128.
#define B_N   2
#define T_LEN 4096
#define H_N   16
#define D_K   128
#define D_V   128
#define COLS  16   // columns per block
#define LPC   16   // lanes per column (one DPP row)
#define EPT   8    // state elements per thread = D_K / LPC
#define CHUNK 16   // steps staged per LDS buffer
#define NCH   (T_LEN / CHUNK)

#define STEP_B   8192u  // bytes per step in k, q, v (16*128*4)
#define AB_B     64u    // bytes per step in alpha, beta (16*4)
#define OSTRIDE  (H_N * D_V)

typedef float f32x4 __attribute__((ext_vector_type(4)));

// ---- DPP helpers: sum over a 16-lane row, broadcast to all 16 lanes.
template <int CTRL>
__device__ __forceinline__ float dpp_add(float x) {
  int y = __builtin_amdgcn_update_dpp(0, __float_as_int(x), CTRL, 0xF, 0xF, true);
  return x + __int_as_float(y);
}
__device__ __forceinline__ float red16(float x) {
  x = dpp_add<0xB1>(x);   // quad_perm xor 1
  x = dpp_add<0x4E>(x);   // quad_perm xor 2
  x = dpp_add<0x124>(x);  // row_ror:4
  x = dpp_add<0x128>(x);  // row_ror:8
  return x;
}

// Async global->LDS (HW path; vmcnt, drained by __syncthreads).
#define GLDS16(gp, lp)                                                        \
  __builtin_amdgcn_global_load_lds(                                           \
      (const __attribute__((address_space(1))) void*)(gp),                    \
      (__attribute__((address_space(3))) void*)(lp), 16, 0, 0)
#define GLDS4(gp, lp)                                                         \
  __builtin_amdgcn_global_load_lds(                                           \
      (const __attribute__((address_space(1))) void*)(gp),                    \
      (__attribute__((address_space(3))) void*)(lp), 4, 0, 0)

extern "C" __global__ void __launch_bounds__(256, 1) gdn_kernel(
    const float* __restrict__ q, const float* __restrict__ k,
    const float* __restrict__ v, const float* __restrict__ al,
    const float* __restrict__ be, const float* __restrict__ S0,
    float* __restrict__ out) {
  // LDS double buffers: k,q 8KB each; v 1KB; a,b 256B each -> 34.5KB total.
  __shared__ float kb[2][CHUNK * D_K];
  __shared__ float qb[2][CHUNK * D_K];
  __shared__ float vb[2][CHUNK * COLS];
  __shared__ float abuf[2][64];
  __shared__ float bbuf[2][64];

  // XCD-affinity decode: the 8 column-group blocks of one (b,h) share
  // (blockIdx mod 8) -> same XCD under round-robin dispatch.
  const int bid = blockIdx.x;
  const int bh = bid & 31;   // (b,h)
  const int g = bid >> 5;    // column group 0..7
  const int b = bh >> 4;
  const int h = bh & 15;
  const int tid = threadIdx.x;
  const int cl = tid >> 4;   // column within group (0..15)
  const int li = tid & 15;   // lane within column
  const int lane = tid & 63;
  const int wid = tid >> 6;  // wave 0..3
  const int col = g * COLS + cl;
  const int d0 = li * EPT;

  const size_t bh_qk = ((size_t)b * T_LEN * H_N + h) * (size_t)D_K;
  const size_t bh_v = ((size_t)b * T_LEN * H_N + h) * (size_t)D_V;
  const size_t bh_ab = (size_t)b * T_LEN * H_N + h;

  // ---- staging source addresses (per-lane, chunk-0; advance by const/chunk)
  // k/q: chunk = 16 rows x 512B, global row stride 8192B. Wave w covers flat
  // bytes [w*2048, (w+1)*2048) via two width-16 calls (1KB each).
  const int fo0 = wid * 2048 + lane * 16;
  const int fo1 = fo0 + 1024;
  const char* kg0 = (const char*)(k + bh_qk) + (size_t)(fo0 >> 9) * STEP_B + (fo0 & 511);
  const char* kg1 = (const char*)(k + bh_qk) + (size_t)(fo1 >> 9) * STEP_B + (fo1 & 511);
  const char* qg0 = (const char*)(q + bh_qk) + (size_t)(fo0 >> 9) * STEP_B + (fo0 & 511);
  const char* qg1 = (const char*)(q + bh_qk) + (size_t)(fo1 >> 9) * STEP_B + (fo1 & 511);
  // v (wave 0): chunk = 16 rows x 64B -> one width-16 call.
  const int fv = lane * 16;
  const char* vg = (const char*)(v + bh_v + g * COLS) + (size_t)(fv >> 6) * STEP_B + (fv & 63);
  // a,b (waves 1,2): 16 scalars, stride 64B; lanes >=16 clamp (write junk pad).
  const int lcl = lane < 16 ? lane : 15;
  const char* ag = (const char*)(al + bh_ab) + (size_t)lcl * AB_B;
  const char* bg = (const char*)(be + bh_ab) + (size_t)lcl * AB_B;

#define STAGE(CI, P)                                                          \
  do {                                                                        \
    const size_t off = (size_t)(CI) * (CHUNK * STEP_B);                       \
    const size_t offab = (size_t)(CI) * (CHUNK * AB_B);                       \
    GLDS16(kg0 + off, &kb[P][wid * 512]);                                     \
    GLDS16(kg1 + off, &kb[P][wid * 512 + 256]);                               \
    GLDS16(qg0 + off, &qb[P][wid * 512]);                                     \
    GLDS16(qg1 + off, &qb[P][wid * 512 + 256]);                               \
    if (wid == 0) GLDS16(vg + off, &vb[P][0]);                                \
    else if (wid == 1) GLDS4(ag + offab, &abuf[P][0]);                        \
    else if (wid == 2) GLDS4(bg + offab, &bbuf[P][0]);                        \
  } while (0)

  // ---- initial state: s[j] = S0[b,h,d0+j,col]
  float s[EPT];
  const float* s0p = S0 + ((size_t)(b * H_N + h) * D_K + d0) * (size_t)D_V + col;
#pragma unroll
  for (int j = 0; j < EPT; ++j) s[j] = s0p[(size_t)j * D_V];

  STAGE(0, 0);
  __syncthreads();  // drains vmcnt -> chunk 0 resident

  float* op = out + bh_v + col;

  for (int ci = 0; ci < NCH; ++ci) {
    const int p = ci & 1;
    if (ci + 1 < NCH) STAGE(ci + 1, p ^ 1);

    const float* kc = kb[p];
    const float* qc = qb[p];
    const float* vc = vb[p];
    const float* ac = abuf[p];
    const float* bc = bbuf[p];

#pragma unroll
    for (int j = 0; j < CHUNK; ++j) {
      f32x4 kA = *(const f32x4*)(kc + j * D_K + d0);
      f32x4 kB = *(const f32x4*)(kc + j * D_K + d0 + 4);
      f32x4 qA = *(const f32x4*)(qc + j * D_K + d0);
      f32x4 qB = *(const f32x4*)(qc + j * D_K + d0 + 4);
      float vv = vc[j * COLS + cl];
      float aa = ac[j];
      float bv = bc[j];

      float kk[8] = {kA.x, kA.y, kA.z, kA.w, kB.x, kB.y, kB.z, kB.w};
      float qq[8] = {qA.x, qA.y, qA.z, qA.w, qB.x, qB.y, qB.z, qB.w};
      // Three dots, 2 accumulators each (dep depth 4).
      float pk0 = kk[0] * s[0], pk1 = kk[1] * s[1];
      float pu0 = qq[0] * s[0], pu1 = qq[1] * s[1];
      float pg0 = kk[0] * qq[0], pg1 = kk[1] * qq[1];
#pragma unroll
      for (int m = 2; m < 8; m += 2) {
        pk0 = fmaf(kk[m], s[m], pk0);    pk1 = fmaf(kk[m + 1], s[m + 1], pk1);
        pu0 = fmaf(qq[m], s[m], pu0);    pu1 = fmaf(qq[m + 1], s[m + 1], pu1);
        pg0 = fmaf(kk[m], qq[m], pg0);   pg1 = fmaf(kk[m + 1], qq[m + 1], pg1);
      }
      float pk = red16(pk0 + pk1);
      float pu = red16(pu0 + pu1);
      float pg = red16(pg0 + pg1);
      // tmp = b*(v - a*(k.S)); off-path scalars precomputed.
      float tmp = fmaf(-(bv * aa), pk, bv * vv);
#pragma unroll
      for (int m = 0; m < 8; ++m) s[m] = fmaf(aa, s[m], kk[m] * tmp);
      // o = a*(q.S_old) + (k.q)*tmp
      if (li == 0) op[(size_t)(ci * CHUNK + j) * OSTRIDE] = fmaf(pg, tmp, aa * pu);
    }
    __syncthreads();  // all waves done with buf p; next chunk's loads landed
  }

  // ---- final state: S_final[b,h,d,col]
  float* sf = out + (size_t)B_N * T_LEN * H_N * D_V +
              ((size_t)(b * H_N + h) * D_K + d0) * (size_t)D_V + col;
#pragma unroll
  for (int j = 0; j < EPT; ++j) sf[(size_t)j * D_V] = s[j];
}

extern "C" void kernel_launch(void* const* d_in, const int* in_sizes, int n_in,
                              void* d_out, int out_size, void* d_ws,
                              size_t ws_size, hipStream_t stream) {
  const float* q = (const float*)d_in[0];
  const float* k = (const float*)d_in[1];
  const float* v = (const float*)d_in[2];
  const float* al = (const float*)d_in[3];
  const float* be = (const float*)d_in[4];
  const float* S0 = (const float*)d_in[5];
  float* out = (float*)d_out;

  dim3 grid(B_N * H_N * (D_V / COLS));  // 256 blocks: one (b,h,col-group) each
  dim3 block(COLS * LPC);               // 256 threads = 4 waves
  gdn_kernel<<<grid, block, 0, stream>>>(q, k, v, al, be, S0, out);
}

// Round 6
// 344.555 us; speedup vs baseline: 5.0500x; 2.2492x over previous
//
#include <hip/hip_runtime.h>

// Problem dims: B=2, T=4096, H=16, Dk=Dv=128. Chunked delta rule, L=64.
#define T_LEN 4096
#define H_N   16
#define DK    128
#define DV    128
#define LCH   64
#define NCH   64

typedef float f32x4 __attribute__((ext_vector_type(4)));
typedef short s16x8 __attribute__((ext_vector_type(8)));

// workspace layout per (head,chunk), bytes
#define OFF_U0 0        // 64x128 f32
#define OFF_W  32768    // 64x128 bf16 (negated W)
#define OFF_Q  49152    // 64x128 bf16 (gamma-less Q)
#define OFF_KD 65536    // 128x64 bf16 (Kd transposed: [d][j] = rr_j k[j][d])
#define OFF_G  81920    // 64x64 bf16
#define OFF_GV 90112    // 64 f32 (g = cumsum ln a)
#define CH_B   90368ull
#define WS_NEED (2048ull * CH_B)

#define SWZ(row) (((row)&7) << 4)

__device__ __forceinline__ unsigned short f2b(float x) {
  unsigned u = __float_as_uint(x);
  return (unsigned short)((u + 0x7FFF + ((u >> 16) & 1)) >> 16);
}

// ---------------- Phase 1: per-(head,chunk) UT transform ----------------
__device__ void solve64(float* RHS, const float* A, int tid) {
  // (I+A) Y = RHS, A strictly lower 64x64; blocked forward substitution.
#pragma unroll 1
  for (int I = 0; I < 4; ++I) {
    if (I > 0) {
      // rows [16I,16I+16) -= A[rows, 0:16I] * Y[0:16I]
      const int i2 = 16 * I + (tid >> 4), cg = tid & 15;
      float* rp = RHS + i2 * 128 + cg * 8;
      float acc[8];
#pragma unroll
      for (int m = 0; m < 8; ++m) acc[m] = rp[m];
      for (int j = 0; j < 16 * I; ++j) {
        float a = A[i2 * 64 + j];
        const float* yp = RHS + j * 128 + cg * 8;
#pragma unroll
        for (int m = 0; m < 8; ++m) acc[m] = fmaf(-a, yp[m], acc[m]);
      }
#pragma unroll
      for (int m = 0; m < 8; ++m) rp[m] = acc[m];
      __syncthreads();
    }
    // diagonal 16x16 block, serial rows, 128 threads (1 col each)
    if (tid < 128) {
      const int col = tid;
      float y[16];
#pragma unroll
      for (int r = 0; r < 16; ++r) y[r] = RHS[(16 * I + r) * 128 + col];
#pragma unroll
      for (int r = 1; r < 16; ++r) {
        float t = y[r];
#pragma unroll
        for (int j = 0; j < 15; ++j)
          if (j < r) t = fmaf(-A[(16 * I + r) * 64 + 16 * I + j], y[j], t);
        y[r] = t;
      }
#pragma unroll
      for (int r = 0; r < 16; ++r) RHS[(16 * I + r) * 128 + col] = y[r];
    }
    __syncthreads();
  }
}

extern "C" __global__ void __launch_bounds__(256) gdn_p1(
    const float* __restrict__ q, const float* __restrict__ k,
    const float* __restrict__ v, const float* __restrict__ al,
    const float* __restrict__ be, char* __restrict__ ws) {
  __shared__ unsigned char big[32768];
  __shared__ float A_s[64 * 64];
  __shared__ float g_s[64], bb_s[64], sc_s[64];
  unsigned char* Kb = big;            // 64x128 bf16, swizzled
  unsigned char* Qb = big + 16384;    // 64x128 bf16, swizzled
  float* RHS = (float*)big;           // 64x128 f32 (aliases Kb/Qb, used later)

  const int bid = blockIdx.x;
  const int bh = bid & 31, c = bid >> 5;
  const int b = bh >> 4, h = bh & 15;
  const int tid = threadIdx.x;
  const int t0 = c * LCH;
  char* wsc = ws + (size_t)(bh * 64 + c) * CH_B;

  // ---- gates: g = inclusive cumsum(ln a), gamma, store g
  if (tid < 64) {
    size_t gi = (size_t)(b * T_LEN + t0 + tid) * H_N + h;
    g_s[tid] = __logf(al[gi]);
    bb_s[tid] = be[gi];
  }
  __syncthreads();
  if (tid == 0) {
    float r = 0.f;
    for (int i = 0; i < 64; ++i) { r += g_s[i]; g_s[i] = r; }
  }
  __syncthreads();
  if (tid < 64) {
    sc_s[tid] = __expf(g_s[tid]);                    // gamma_i
    *(float*)(wsc + OFF_GV + tid * 4) = g_s[tid];
  }

  // ---- stage K,Q as bf16 (swizzled) in LDS; also store Qbf to ws
  for (int idx = tid; idx < 1024; idx += 256) {
    int row = idx >> 4, grp = idx & 15;
    size_t go = ((size_t)(b * T_LEN + t0 + row) * H_N + h) * DK + grp * 8;
    float4 ka = *(const float4*)(k + go);
    float4 kb2 = *(const float4*)(k + go + 4);
    float4 qa = *(const float4*)(q + go);
    float4 qb2 = *(const float4*)(q + go + 4);
    union { unsigned short u[8]; uint4 v4; } tk, tq;
    tk.u[0] = f2b(ka.x); tk.u[1] = f2b(ka.y); tk.u[2] = f2b(ka.z); tk.u[3] = f2b(ka.w);
    tk.u[4] = f2b(kb2.x); tk.u[5] = f2b(kb2.y); tk.u[6] = f2b(kb2.z); tk.u[7] = f2b(kb2.w);
    tq.u[0] = f2b(qa.x); tq.u[1] = f2b(qa.y); tq.u[2] = f2b(qa.z); tq.u[3] = f2b(qa.w);
    tq.u[4] = f2b(qb2.x); tq.u[5] = f2b(qb2.y); tq.u[6] = f2b(qb2.z); tq.u[7] = f2b(qb2.w);
    int la = (row * 256 + grp * 16) ^ SWZ(row);
    *(uint4*)(Kb + la) = tk.v4;
    *(uint4*)(Qb + la) = tq.v4;
    *(uint4*)(wsc + OFF_Q + row * 256 + grp * 16) = tq.v4;  // unswizzled
  }
  __syncthreads();

  // ---- KK^T and QK^T via MFMA; scale+mask -> A_s (f32 LDS), G (bf16 ws)
  const int w = tid >> 6, l = tid & 63, li = l & 15, hi = l >> 4;
  f32x4 aK[4], aQ[4];
#pragma unroll
  for (int jt = 0; jt < 4; ++jt) { aK[jt] = (f32x4){0, 0, 0, 0}; aQ[jt] = (f32x4){0, 0, 0, 0}; }
#pragma unroll
  for (int ks = 0; ks < 4; ++ks) {
    int rowA = 16 * w + li;
    int oa = (rowA * 256 + ks * 64 + hi * 16) ^ SWZ(rowA);
    s16x8 fa = *(const s16x8*)(Kb + oa);
    s16x8 fq = *(const s16x8*)(Qb + oa);
#pragma unroll
    for (int jt = 0; jt < 4; ++jt) {
      int rowB = 16 * jt + li;
      s16x8 fb = *(const s16x8*)(Kb + ((rowB * 256 + ks * 64 + hi * 16) ^ SWZ(rowB)));
      aK[jt] = __builtin_amdgcn_mfma_f32_16x16x32_bf16(fa, fb, aK[jt], 0, 0, 0);
      aQ[jt] = __builtin_amdgcn_mfma_f32_16x16x32_bf16(fq, fb, aQ[jt], 0, 0, 0);
    }
  }
#pragma unroll
  for (int jt = 0; jt < 4; ++jt)
#pragma unroll
    for (int r = 0; r < 4; ++r) {
      int i = 16 * w + hi * 4 + r, j = 16 * jt + li;   // C layout (m89)
      float e = __expf(g_s[i] - g_s[j]);
      A_s[i * 64 + j] = (j < i) ? bb_s[i] * e * aK[jt][r] : 0.f;
      *(unsigned short*)(wsc + OFF_G + (i * 64 + j) * 2) =
          f2b((j <= i) ? e * aQ[jt][r] : 0.f);
    }
  __syncthreads();

  // ---- solve U0: RHS = diag(b) V
  for (int idx = tid; idx < 2048; idx += 256) {
    int row = idx >> 5, c4 = idx & 31;
    float4 vv = *(const float4*)(v + ((size_t)(b * T_LEN + t0 + row) * H_N + h) * DV + c4 * 4);
    float s = bb_s[row];
    float4 o = {s * vv.x, s * vv.y, s * vv.z, s * vv.w};
    *(float4*)(RHS + row * 128 + c4 * 4) = o;
  }
  __syncthreads();
  solve64(RHS, A_s, tid);
  for (int idx = tid; idx < 2048; idx += 256)
    *(float4*)(wsc + OFF_U0 + idx * 16) = *(const float4*)(RHS + idx * 4);
  __syncthreads();

  // ---- solve W: RHS = diag(b*gamma) K; store negated bf16
  for (int idx = tid; idx < 2048; idx += 256) {
    int row = idx >> 5, c4 = idx & 31;
    float4 kv = *(const float4*)(k + ((size_t)(b * T_LEN + t0 + row) * H_N + h) * DK + c4 * 4);
    float s = bb_s[row] * sc_s[row];
    float4 o = {s * kv.x, s * kv.y, s * kv.z, s * kv.w};
    *(float4*)(RHS + row * 128 + c4 * 4) = o;
  }
  __syncthreads();
  solve64(RHS, A_s, tid);
  for (int idx = tid; idx < 1024; idx += 256) {
    int row = idx >> 4, g8 = idx & 15;
    const float* p = RHS + row * 128 + g8 * 8;
    union { unsigned short u[8]; uint4 v4; } t;
#pragma unroll
    for (int e = 0; e < 8; ++e) t.u[e] = f2b(-p[e]);
    *(uint4*)(wsc + OFF_W + row * 256 + g8 * 16) = t.v4;
  }
  __syncthreads();

  // ---- Kdt[d][j] = exp(g63-g_j) * k[j][d], two half passes via padded LDS
  if (tid < 64) sc_s[tid] = __expf(g_s[63] - g_s[tid]);  // rr_j
  __syncthreads();
  float* Kf = (float*)big;  // 32 x 132 f32
#pragma unroll 1
  for (int p = 0; p < 2; ++p) {
    for (int idx = tid; idx < 1024; idx += 256) {
      int r = idx >> 5, c4 = idx & 31;
      float4 kv = *(const float4*)(k + ((size_t)(b * T_LEN + t0 + 32 * p + r) * H_N + h) * DK + c4 * 4);
      *(float4*)(Kf + r * 132 + c4 * 4) = kv;
    }
    __syncthreads();
#pragma unroll
    for (int m = 0; m < 16; ++m) {
      int flat = m * 256 + tid;            // 128 d x 32 j
      int j32 = flat & 31, d = flat >> 5;
      float val = sc_s[32 * p + j32] * Kf[j32 * 132 + d];
      *(unsigned short*)(wsc + OFF_KD + (d * 64 + 32 * p + j32) * 2) = f2b(val);
    }
    __syncthreads();
  }
}

// ---------------- Phase 2: serial chunk recurrence, MFMA ----------------
extern "C" __global__ void __launch_bounds__(256) gdn_p2(
    const float* __restrict__ S0, float* __restrict__ out,
    const char* __restrict__ ws) {
  __shared__ unsigned char Stb[16 * 256];  // S^T bf16 [n][d], swizzled rows
  __shared__ unsigned char Ytb[16 * 128];  // Y^T bf16 [n][j], swizzled rows
  __shared__ float g2[64];

  const int bid = blockIdx.x;
  const int bh = bid & 31, s = bid >> 5;
  const int b = bh >> 4, h = bh & 15;
  const int tid = threadIdx.x;
  const int w = tid >> 6, l = tid & 63, li = l & 15, hi = l >> 4;

  float S[2][4];
#pragma unroll
  for (int t = 0; t < 2; ++t)
#pragma unroll
    for (int r = 0; r < 4; ++r) {
      int d = (w + 4 * t) * 16 + hi * 4 + r;
      S[t][r] = S0[((size_t)bh * 128 + d) * 128 + s * 16 + li];
    }
#define WRITE_ST()                                                          \
  do {                                                                      \
    _Pragma("unroll") for (int t = 0; t < 2; ++t)                           \
        _Pragma("unroll") for (int r = 0; r < 4; r += 2) {                  \
      int d = (w + 4 * t) * 16 + hi * 4 + r;                                \
      unsigned pk = (unsigned)f2b(S[t][r]) | ((unsigned)f2b(S[t][r + 1]) << 16); \
      *(unsigned*)(Stb + ((li * 256 + d * 2) ^ SWZ(li))) = pk;              \
    }                                                                       \
  } while (0)
  WRITE_ST();
  __syncthreads();

#pragma unroll 1
  for (int c = 0; c < NCH; ++c) {
    const char* wsc = ws + (size_t)(bh * 64 + c) * CH_B;
    if (tid < 64) g2[tid] = *(const float*)(wsc + OFF_GV + tid * 4);

    // Y = U0 + Wn * S   (wave w -> rows 16w..16w+15)
    f32x4 Y;
#pragma unroll
    for (int r = 0; r < 4; ++r)
      Y[r] = *(const float*)(wsc + OFF_U0 + (size_t)((16 * w + hi * 4 + r) * 128 + s * 16 + li) * 4);
#pragma unroll
    for (int ks = 0; ks < 4; ++ks) {
      s16x8 fa = *(const s16x8*)(wsc + OFF_W + ((16 * w + li) * 128 + ks * 32 + hi * 8) * 2);
      s16x8 fb = *(const s16x8*)(Stb + ((li * 256 + (ks * 32 + hi * 8) * 2) ^ SWZ(li)));
      Y = __builtin_amdgcn_mfma_f32_16x16x32_bf16(fa, fb, Y, 0, 0, 0);
    }
#pragma unroll
    for (int r = 0; r < 4; r += 2) {  // Y^T -> LDS
      int j = 16 * w + hi * 4 + r;
      unsigned pk = (unsigned)f2b(Y[r]) | ((unsigned)f2b(Y[r + 1]) << 16);
      *(unsigned*)(Ytb + ((li * 128 + j * 2) ^ SWZ(li))) = pk;
    }
    __syncthreads();

    // O = diag(gamma) Q S + G Y
    f32x4 O = {0, 0, 0, 0};
#pragma unroll
    for (int ks = 0; ks < 4; ++ks) {
      s16x8 fa = *(const s16x8*)(wsc + OFF_Q + ((16 * w + li) * 128 + ks * 32 + hi * 8) * 2);
      s16x8 fb = *(const s16x8*)(Stb + ((li * 256 + (ks * 32 + hi * 8) * 2) ^ SWZ(li)));
      O = __builtin_amdgcn_mfma_f32_16x16x32_bf16(fa, fb, O, 0, 0, 0);
    }
#pragma unroll
    for (int r = 0; r < 4; ++r) O[r] *= __expf(g2[16 * w + hi * 4 + r]);
#pragma unroll
    for (int ks = 0; ks < 2; ++ks) {
      s16x8 fa = *(const s16x8*)(wsc + OFF_G + ((16 * w + li) * 64 + ks * 32 + hi * 8) * 2);
      s16x8 fb = *(const s16x8*)(Ytb + ((li * 128 + (ks * 32 + hi * 8) * 2) ^ SWZ(li)));
      O = __builtin_amdgcn_mfma_f32_16x16x32_bf16(fa, fb, O, 0, 0, 0);
    }
#pragma unroll
    for (int r = 0; r < 4; ++r) {
      size_t oi = ((size_t)(b * T_LEN + c * 64 + 16 * w + hi * 4 + r) * H_N + h) * DV + s * 16 + li;
      out[oi] = O[r];
    }

    // S = gamma_end * S + Kd^T Y
    float ge = __expf(g2[63]);
#pragma unroll
    for (int t = 0; t < 2; ++t) {
      f32x4 acc;
#pragma unroll
      for (int r = 0; r < 4; ++r) acc[r] = ge * S[t][r];
#pragma unroll
      for (int ks = 0; ks < 2; ++ks) {
        s16x8 fa = *(const s16x8*)(wsc + OFF_KD + (((w + 4 * t) * 16 + li) * 64 + ks * 32 + hi * 8) * 2);
        s16x8 fb = *(const s16x8*)(Ytb + ((li * 128 + (ks * 32 + hi * 8) * 2) ^ SWZ(li)));
        acc = __builtin_amdgcn_mfma_f32_16x16x32_bf16(fa, fb, acc, 0, 0, 0);
      }
#pragma unroll
      for (int r = 0; r < 4; ++r) S[t][r] = acc[r];
    }
    __syncthreads();
    WRITE_ST();
    __syncthreads();
  }

  // final state
#pragma unroll
  for (int t = 0; t < 2; ++t)
#pragma unroll
    for (int r = 0; r < 4; ++r) {
      int d = (w + 4 * t) * 16 + hi * 4 + r;
      out[(size_t)(2 * T_LEN * H_N * DV) + ((size_t)bh * 128 + d) * 128 + s * 16 + li] = S[t][r];
    }
}

// ---------------- Fallback (round-5 kernel, used only if ws too small) ----
#define COLS 16
#define CHUNK 16
#define STEP_B 8192u
#define AB_B 64u
#define OSTRIDE (H_N * DV)
template <int CTRL>
__device__ __forceinline__ float dpp_add(float x) {
  int y = __builtin_amdgcn_update_dpp(0, __float_as_int(x), CTRL, 0xF, 0xF, true);
  return x + __int_as_float(y);
}
__device__ __forceinline__ float red16(float x) {
  x = dpp_add<0xB1>(x); x = dpp_add<0x4E>(x);
  x = dpp_add<0x124>(x); x = dpp_add<0x128>(x);
  return x;
}
#define GLDS16(gp, lp) __builtin_amdgcn_global_load_lds((const __attribute__((address_space(1))) void*)(gp), (__attribute__((address_space(3))) void*)(lp), 16, 0, 0)
#define GLDS4(gp, lp) __builtin_amdgcn_global_load_lds((const __attribute__((address_space(1))) void*)(gp), (__attribute__((address_space(3))) void*)(lp), 4, 0, 0)
extern "C" __global__ void __launch_bounds__(256, 1) gdn_fallback(
    const float* __restrict__ q, const float* __restrict__ k,
    const float* __restrict__ v, const float* __restrict__ al,
    const float* __restrict__ be, const float* __restrict__ S0,
    float* __restrict__ out) {
  __shared__ float kb[2][CHUNK * DK];
  __shared__ float qb[2][CHUNK * DK];
  __shared__ float vb[2][CHUNK * COLS];
  __shared__ float abuf[2][64];
  __shared__ float bbuf[2][64];
  const int bid = blockIdx.x;
  const int bh = bid & 31, g = bid >> 5;
  const int b = bh >> 4, h = bh & 15;
  const int tid = threadIdx.x;
  const int cl = tid >> 4, li = tid & 15, lane = tid & 63, wid = tid >> 6;
  const int col = g * COLS + cl, d0 = li * 8;
  const size_t bh_qk = ((size_t)b * T_LEN * H_N + h) * DK;
  const size_t bh_v = ((size_t)b * T_LEN * H_N + h) * DV;
  const size_t bh_ab = (size_t)b * T_LEN * H_N + h;
  const int fo0 = wid * 2048 + lane * 16, fo1 = fo0 + 1024;
  const char* kg0 = (const char*)(k + bh_qk) + (size_t)(fo0 >> 9) * STEP_B + (fo0 & 511);
  const char* kg1 = (const char*)(k + bh_qk) + (size_t)(fo1 >> 9) * STEP_B + (fo1 & 511);
  const char* qg0 = (const char*)(q + bh_qk) + (size_t)(fo0 >> 9) * STEP_B + (fo0 & 511);
  const char* qg1 = (const char*)(q + bh_qk) + (size_t)(fo1 >> 9) * STEP_B + (fo1 & 511);
  const int fv = lane * 16;
  const char* vg = (const char*)(v + bh_v + g * COLS) + (size_t)(fv >> 6) * STEP_B + (fv & 63);
  const int lcl = lane < 16 ? lane : 15;
  const char* ag = (const char*)(al + bh_ab) + (size_t)lcl * AB_B;
  const char* bg = (const char*)(be + bh_ab) + (size_t)lcl * AB_B;
#define STAGE(CI, P) do { \
    const size_t off = (size_t)(CI) * (CHUNK * STEP_B); \
    const size_t offab = (size_t)(CI) * (CHUNK * AB_B); \
    GLDS16(kg0 + off, &kb[P][wid * 512]); GLDS16(kg1 + off, &kb[P][wid * 512 + 256]); \
    GLDS16(qg0 + off, &qb[P][wid * 512]); GLDS16(qg1 + off, &qb[P][wid * 512 + 256]); \
    if (wid == 0) GLDS16(vg + off, &vb[P][0]); \
    else if (wid == 1) GLDS4(ag + offab, &abuf[P][0]); \
    else if (wid == 2) GLDS4(bg + offab, &bbuf[P][0]); \
  } while (0)
  float sv[8];
  const float* s0p = S0 + ((size_t)(b * H_N + h) * DK + d0) * DV + col;
#pragma unroll
  for (int j = 0; j < 8; ++j) sv[j] = s0p[(size_t)j * DV];
  STAGE(0, 0);
  __syncthreads();
  float* op = out + bh_v + col;
  for (int ci = 0; ci < T_LEN / CHUNK; ++ci) {
    const int p = ci & 1;
    if (ci + 1 < T_LEN / CHUNK) STAGE(ci + 1, p ^ 1);
    const float* kc = kb[p]; const float* qc = qb[p]; const float* vc = vb[p];
    const float* ac = abuf[p]; const float* bc = bbuf[p];
#pragma unroll
    for (int j = 0; j < CHUNK; ++j) {
      f32x4 kA = *(const f32x4*)(kc + j * DK + d0);
      f32x4 kB = *(const f32x4*)(kc + j * DK + d0 + 4);
      f32x4 qA = *(const f32x4*)(qc + j * DK + d0);
      f32x4 qB = *(const f32x4*)(qc + j * DK + d0 + 4);
      float vv = vc[j * COLS + cl], aa = ac[j], bv = bc[j];
      float kk[8] = {kA[0], kA[1], kA[2], kA[3], kB[0], kB[1], kB[2], kB[3]};
      float qq[8] = {qA[0], qA[1], qA[2], qA[3], qB[0], qB[1], qB[2], qB[3]};
      float pk0 = kk[0] * sv[0], pk1 = kk[1] * sv[1];
      float pu0 = qq[0] * sv[0], pu1 = qq[1] * sv[1];
      float pg0 = kk[0] * qq[0], pg1 = kk[1] * qq[1];
#pragma unroll
      for (int m = 2; m < 8; m += 2) {
        pk0 = fmaf(kk[m], sv[m], pk0); pk1 = fmaf(kk[m + 1], sv[m + 1], pk1);
        pu0 = fmaf(qq[m], sv[m], pu0); pu1 = fmaf(qq[m + 1], sv[m + 1], pu1);
        pg0 = fmaf(kk[m], qq[m], pg0); pg1 = fmaf(kk[m + 1], qq[m + 1], pg1);
      }
      float pk = red16(pk0 + pk1), pu = red16(pu0 + pu1), pg = red16(pg0 + pg1);
      float tmp = fmaf(-(bv * aa), pk, bv * vv);
#pragma unroll
      for (int m = 0; m < 8; ++m) sv[m] = fmaf(aa, sv[m], kk[m] * tmp);
      if (li == 0) op[(size_t)(ci * CHUNK + j) * OSTRIDE] = fmaf(pg, tmp, aa * pu);
    }
    __syncthreads();
  }
  float* sf = out + (size_t)2 * T_LEN * H_N * DV + ((size_t)(b * H_N + h) * DK + d0) * DV + col;
#pragma unroll
  for (int j = 0; j < 8; ++j) sf[(size_t)j * DV] = sv[j];
}

extern "C" void kernel_launch(void* const* d_in, const int* in_sizes, int n_in,
                              void* d_out, int out_size, void* d_ws,
                              size_t ws_size, hipStream_t stream) {
  const float* q = (const float*)d_in[0];
  const float* k = (const float*)d_in[1];
  const float* v = (const float*)d_in[2];
  const float* al = (const float*)d_in[3];
  const float* be = (const float*)d_in[4];
  const float* S0 = (const float*)d_in[5];
  float* out = (float*)d_out;

  if (ws_size >= WS_NEED) {
    gdn_p1<<<dim3(2048), dim3(256), 0, stream>>>(q, k, v, al, be, (char*)d_ws);
    gdn_p2<<<dim3(256), dim3(256), 0, stream>>>(S0, out, (const char*)d_ws);
  } else {
    gdn_fallback<<<dim3(256), dim3(256), 0, stream>>>(q, k, v, al, be, S0, out);
  }
}

// Round 7
// 296.565 us; speedup vs baseline: 5.8672x; 1.1618x over previous
//
#include <hip/hip_runtime.h>

// Problem dims: B=2, T=4096, H=16, Dk=Dv=128. Chunked delta rule, L=64.
#define T_LEN 4096
#define H_N   16
#define DK    128
#define DV    128
#define LCH   64
#define NCH   64

typedef float f32x4 __attribute__((ext_vector_type(4)));
typedef short s16x8 __attribute__((ext_vector_type(8)));

// workspace layout per (head,chunk), bytes
#define OFF_U0 0        // [8 slices][64 rows][16 cols] f32 (sliced-contiguous)
#define OFF_W  32768    // 64x128 bf16, XOR-swizzled rows (negated W)
#define OFF_Q  49152    // 64x128 bf16, XOR-swizzled rows (gamma-less Q)
#define OFF_KD 65536    // 128x64 bf16, XOR-swizzled rows ([d][j] = rr_j k[j][d])
#define OFF_G  81920    // 64x64 bf16, XOR-swizzled rows
#define OFF_GM 90112    // 64 f32 (gamma_i = exp(cumsum ln a))
#define CH_B   90368ull
#define WS_NEED (2048ull * CH_B)

#define SWZ(row) (((row)&7) << 4)

__device__ __forceinline__ unsigned short f2b(float x) {
  unsigned u = __float_as_uint(x);
  return (unsigned short)((u + 0x7FFF + ((u >> 16) & 1)) >> 16);
}

// Async global->LDS (vmcnt; drained only by full __syncthreads)
#define GLDS16(gp, lp)                                                        \
  __builtin_amdgcn_global_load_lds(                                           \
      (const __attribute__((address_space(1))) void*)(gp),                    \
      (__attribute__((address_space(3))) void*)(lp), 16, 0, 0)
#define GLDS4(gp, lp)                                                         \
  __builtin_amdgcn_global_load_lds(                                           \
      (const __attribute__((address_space(1))) void*)(gp),                    \
      (__attribute__((address_space(3))) void*)(lp), 4, 0, 0)

// LDS-only barrier: orders ds_write/ds_read across waves WITHOUT draining
// vmcnt (staged global_load_lds stays in flight). 8-phase-template pattern.
#define LBAR()                                                                \
  do {                                                                        \
    asm volatile("s_waitcnt lgkmcnt(0)" ::: "memory");                        \
    __builtin_amdgcn_s_barrier();                                             \
    __builtin_amdgcn_sched_barrier(0);                                        \
  } while (0)

// ---------------- Phase 1: per-(head,chunk) UT transform ----------------
__device__ void solve64(float* RHS, const float* A, int tid) {
  // (I+A) Y = RHS, A strictly lower 64x64; blocked forward substitution.
#pragma unroll 1
  for (int I = 0; I < 4; ++I) {
    if (I > 0) {
      const int i2 = 16 * I + (tid >> 4), cg = tid & 15;
      float* rp = RHS + i2 * 128 + cg * 8;
      float acc[8];
#pragma unroll
      for (int m = 0; m < 8; ++m) acc[m] = rp[m];
      for (int j = 0; j < 16 * I; ++j) {
        float a = A[i2 * 64 + j];
        const float* yp = RHS + j * 128 + cg * 8;
#pragma unroll
        for (int m = 0; m < 8; ++m) acc[m] = fmaf(-a, yp[m], acc[m]);
      }
#pragma unroll
      for (int m = 0; m < 8; ++m) rp[m] = acc[m];
      __syncthreads();
    }
    if (tid < 128) {
      const int col = tid;
      float y[16];
#pragma unroll
      for (int r = 0; r < 16; ++r) y[r] = RHS[(16 * I + r) * 128 + col];
#pragma unroll
      for (int r = 1; r < 16; ++r) {
        float t = y[r];
#pragma unroll
        for (int j = 0; j < 15; ++j)
          if (j < r) t = fmaf(-A[(16 * I + r) * 64 + 16 * I + j], y[j], t);
        y[r] = t;
      }
#pragma unroll
      for (int r = 0; r < 16; ++r) RHS[(16 * I + r) * 128 + col] = y[r];
    }
    __syncthreads();
  }
}

extern "C" __global__ void __launch_bounds__(256) gdn_p1(
    const float* __restrict__ q, const float* __restrict__ k,
    const float* __restrict__ v, const float* __restrict__ al,
    const float* __restrict__ be, char* __restrict__ ws) {
  __shared__ unsigned char big[32768];
  __shared__ float A_s[64 * 64];
  __shared__ float g_s[64], bb_s[64], sc_s[64];
  unsigned char* Kb = big;            // 64x128 bf16, swizzled
  unsigned char* Qb = big + 16384;    // 64x128 bf16, swizzled
  float* RHS = (float*)big;           // 64x128 f32 (aliases Kb/Qb, used later)

  const int bid = blockIdx.x;
  const int bh = bid & 31, c = bid >> 5;
  const int b = bh >> 4, h = bh & 15;
  const int tid = threadIdx.x;
  const int t0 = c * LCH;
  char* wsc = ws + (size_t)(bh * 64 + c) * CH_B;

  // ---- gates: g = inclusive cumsum(ln a); store gamma = exp(g)
  if (tid < 64) {
    size_t gi = (size_t)(b * T_LEN + t0 + tid) * H_N + h;
    g_s[tid] = __logf(al[gi]);
    bb_s[tid] = be[gi];
  }
  __syncthreads();
  if (tid == 0) {
    float r = 0.f;
    for (int i = 0; i < 64; ++i) { r += g_s[i]; g_s[i] = r; }
  }
  __syncthreads();
  if (tid < 64) {
    sc_s[tid] = __expf(g_s[tid]);                    // gamma_i
    *(float*)(wsc + OFF_GM + tid * 4) = sc_s[tid];
  }

  // ---- stage K,Q as bf16 (swizzled) in LDS; store Qbf to ws (swizzled)
  for (int idx = tid; idx < 1024; idx += 256) {
    int row = idx >> 4, grp = idx & 15;
    size_t go = ((size_t)(b * T_LEN + t0 + row) * H_N + h) * DK + grp * 8;
    float4 ka = *(const float4*)(k + go);
    float4 kb2 = *(const float4*)(k + go + 4);
    float4 qa = *(const float4*)(q + go);
    float4 qb2 = *(const float4*)(q + go + 4);
    union { unsigned short u[8]; uint4 v4; } tk, tq;
    tk.u[0] = f2b(ka.x); tk.u[1] = f2b(ka.y); tk.u[2] = f2b(ka.z); tk.u[3] = f2b(ka.w);
    tk.u[4] = f2b(kb2.x); tk.u[5] = f2b(kb2.y); tk.u[6] = f2b(kb2.z); tk.u[7] = f2b(kb2.w);
    tq.u[0] = f2b(qa.x); tq.u[1] = f2b(qa.y); tq.u[2] = f2b(qa.z); tq.u[3] = f2b(qa.w);
    tq.u[4] = f2b(qb2.x); tq.u[5] = f2b(qb2.y); tq.u[6] = f2b(qb2.z); tq.u[7] = f2b(qb2.w);
    int la = (row * 256 + grp * 16) ^ SWZ(row);
    *(uint4*)(Kb + la) = tk.v4;
    *(uint4*)(Qb + la) = tq.v4;
    *(uint4*)(wsc + OFF_Q + la) = tq.v4;  // swizzled in ws too
  }
  __syncthreads();

  // ---- KK^T and QK^T via MFMA; scale+mask -> A_s (f32 LDS), G (bf16 ws)
  const int w = tid >> 6, l = tid & 63, li = l & 15, hi = l >> 4;
  f32x4 aK[4], aQ[4];
#pragma unroll
  for (int jt = 0; jt < 4; ++jt) { aK[jt] = (f32x4){0, 0, 0, 0}; aQ[jt] = (f32x4){0, 0, 0, 0}; }
#pragma unroll
  for (int ks = 0; ks < 4; ++ks) {
    int rowA = 16 * w + li;
    int oa = (rowA * 256 + ks * 64 + hi * 16) ^ SWZ(rowA);
    s16x8 fa = *(const s16x8*)(Kb + oa);
    s16x8 fq = *(const s16x8*)(Qb + oa);
#pragma unroll
    for (int jt = 0; jt < 4; ++jt) {
      int rowB = 16 * jt + li;
      s16x8 fb = *(const s16x8*)(Kb + ((rowB * 256 + ks * 64 + hi * 16) ^ SWZ(rowB)));
      aK[jt] = __builtin_amdgcn_mfma_f32_16x16x32_bf16(fa, fb, aK[jt], 0, 0, 0);
      aQ[jt] = __builtin_amdgcn_mfma_f32_16x16x32_bf16(fq, fb, aQ[jt], 0, 0, 0);
    }
  }
#pragma unroll
  for (int jt = 0; jt < 4; ++jt)
#pragma unroll
    for (int r = 0; r < 4; ++r) {
      int i = 16 * w + hi * 4 + r, j = 16 * jt + li;   // C layout (m89)
      float e = __expf(g_s[i] - g_s[j]);
      A_s[i * 64 + j] = (j < i) ? bb_s[i] * e * aK[jt][r] : 0.f;
      *(unsigned short*)(wsc + OFF_G + ((i * 128 + j * 2) ^ SWZ(i))) =
          f2b((j <= i) ? e * aQ[jt][r] : 0.f);
    }
  __syncthreads();

  // ---- solve U0: RHS = diag(b) V; store sliced-contiguous f32
  for (int idx = tid; idx < 2048; idx += 256) {
    int row = idx >> 5, c4 = idx & 31;
    float4 vv = *(const float4*)(v + ((size_t)(b * T_LEN + t0 + row) * H_N + h) * DV + c4 * 4);
    float s = bb_s[row];
    float4 o = {s * vv.x, s * vv.y, s * vv.z, s * vv.w};
    *(float4*)(RHS + row * 128 + c4 * 4) = o;
  }
  __syncthreads();
  solve64(RHS, A_s, tid);
  for (int idx = tid; idx < 2048; idx += 256) {
    int row = idx >> 5, c4 = idx & 31;
    *(float4*)(wsc + OFF_U0 + (c4 >> 2) * 4096 + row * 64 + (c4 & 3) * 16) =
        *(const float4*)(RHS + idx * 4);
  }
  __syncthreads();

  // ---- solve W: RHS = diag(b*gamma) K; store negated bf16 (swizzled)
  for (int idx = tid; idx < 2048; idx += 256) {
    int row = idx >> 5, c4 = idx & 31;
    float4 kv = *(const float4*)(k + ((size_t)(b * T_LEN + t0 + row) * H_N + h) * DK + c4 * 4);
    float s = bb_s[row] * sc_s[row];
    float4 o = {s * kv.x, s * kv.y, s * kv.z, s * kv.w};
    *(float4*)(RHS + row * 128 + c4 * 4) = o;
  }
  __syncthreads();
  solve64(RHS, A_s, tid);
  for (int idx = tid; idx < 1024; idx += 256) {
    int row = idx >> 4, g8 = idx & 15;
    const float* p = RHS + row * 128 + g8 * 8;
    union { unsigned short u[8]; uint4 v4; } t;
#pragma unroll
    for (int e = 0; e < 8; ++e) t.u[e] = f2b(-p[e]);
    *(uint4*)(wsc + OFF_W + ((row * 256 + g8 * 16) ^ SWZ(row))) = t.v4;
  }
  __syncthreads();

  // ---- Kdt[d][j] = exp(g63-g_j) * k[j][d] (swizzled rows of 128B)
  if (tid < 64) sc_s[tid] = __expf(g_s[63] - g_s[tid]);  // rr_j
  __syncthreads();
  float* Kf = (float*)big;  // 32 x 132 f32
#pragma unroll 1
  for (int p = 0; p < 2; ++p) {
    for (int idx = tid; idx < 1024; idx += 256) {
      int r = idx >> 5, c4 = idx & 31;
      float4 kv = *(const float4*)(k + ((size_t)(b * T_LEN + t0 + 32 * p + r) * H_N + h) * DK + c4 * 4);
      *(float4*)(Kf + r * 132 + c4 * 4) = kv;
    }
    __syncthreads();
#pragma unroll
    for (int m = 0; m < 16; ++m) {
      int flat = m * 256 + tid;            // 128 d x 32 j
      int j32 = flat & 31, d = flat >> 5;
      float val = sc_s[32 * p + j32] * Kf[j32 * 132 + d];
      *(unsigned short*)(wsc + OFF_KD + ((d * 128 + (32 * p + j32) * 2) ^ SWZ(d))) = f2b(val);
    }
    __syncthreads();
  }
}

// ---------------- Phase 2: serial chunk recurrence, staged MFMA ----------
extern "C" __global__ void __launch_bounds__(256, 1) gdn_p2(
    const float* __restrict__ S0, float* __restrict__ out,
    const char* __restrict__ ws) {
  // double-buffered staged operands (126KB total incl. Stb/Ytb)
  __shared__ unsigned char Wb[2][16384];
  __shared__ unsigned char Qb[2][16384];
  __shared__ unsigned char KDb[2][16384];
  __shared__ unsigned char Gb[2][8192];
  __shared__ float U0s[2][1024];   // [64 rows][16 cols] slice
  __shared__ float gam[2][64];
  __shared__ unsigned char Stb[4096];  // S^T bf16 [16 col][128 d], swz rows
  __shared__ unsigned char Ytb[2048];  // Y^T bf16 [16 col][64 j], swz rows

  const int bid = blockIdx.x;
  const int bh = bid & 31, s = bid >> 5;   // siblings share (bid mod 8) -> XCD
  const int b = bh >> 4, h = bh & 15;
  const int tid = threadIdx.x;
  const int w = tid >> 6, lane = tid & 63, li = lane & 15, hi = lane >> 4;
  const char* wsbase = ws + (size_t)bh * 64 * CH_B;

#define STG(CI, P)                                                            \
  do {                                                                        \
    const char* c_ = wsbase + (size_t)(CI) * CH_B;                            \
    _Pragma("unroll") for (int j_ = 0; j_ < 4; ++j_) {                        \
      GLDS16(c_ + OFF_W + j_ * 4096 + tid * 16, &Wb[P][j_ * 4096 + w * 1024]); \
      GLDS16(c_ + OFF_Q + j_ * 4096 + tid * 16, &Qb[P][j_ * 4096 + w * 1024]); \
      GLDS16(c_ + OFF_KD + j_ * 4096 + tid * 16, &KDb[P][j_ * 4096 + w * 1024]); \
    }                                                                         \
    _Pragma("unroll") for (int j_ = 0; j_ < 2; ++j_)                          \
      GLDS16(c_ + OFF_G + j_ * 4096 + tid * 16, &Gb[P][j_ * 4096 + w * 1024]); \
    GLDS16(c_ + OFF_U0 + s * 4096 + tid * 16,                                 \
           (unsigned char*)U0s[P] + w * 1024);                                \
    if (w == 0) GLDS4(c_ + OFF_GM + lane * 4, &gam[P][0]);                    \
  } while (0)

  // initial state in registers (C layout): d = (w+4t)*16+hi*4+r, col = s*16+li
  float S[2][4];
#pragma unroll
  for (int t = 0; t < 2; ++t)
#pragma unroll
    for (int r = 0; r < 4; ++r) {
      int d = (w + 4 * t) * 16 + hi * 4 + r;
      S[t][r] = S0[((size_t)bh * 128 + d) * 128 + s * 16 + li];
    }
#define WRITE_ST()                                                            \
  do {                                                                        \
    _Pragma("unroll") for (int t = 0; t < 2; ++t)                             \
        _Pragma("unroll") for (int r = 0; r < 4; r += 2) {                    \
      int d = (w + 4 * t) * 16 + hi * 4 + r;                                  \
      unsigned pk = (unsigned)f2b(S[t][r]) | ((unsigned)f2b(S[t][r + 1]) << 16); \
      *(unsigned*)(Stb + ((li * 256 + d * 2) ^ SWZ(li))) = pk;                \
    }                                                                         \
  } while (0)

  STG(0, 0);
  WRITE_ST();
  __syncthreads();  // drains vmcnt: buf 0 staged, Stb visible

#pragma unroll 1
  for (int c = 0; c < NCH; ++c) {
    const int p = c & 1;
    if (c + 1 < NCH) STG(c + 1, p ^ 1);

    // Stb fragments, shared by Y-phase and O-QS phase
    s16x8 sfb[4];
#pragma unroll
    for (int ks = 0; ks < 4; ++ks)
      sfb[ks] = *(const s16x8*)(Stb + ((li * 256 + ks * 64 + hi * 16) ^ SWZ(li)));

    // Y = U0 + Wn * S   (wave w -> rows 16w..16w+15)
    f32x4 Y;
#pragma unroll
    for (int r = 0; r < 4; ++r) Y[r] = U0s[p][(16 * w + hi * 4 + r) * 16 + li];
#pragma unroll
    for (int ks = 0; ks < 4; ++ks) {
      s16x8 fa = *(const s16x8*)(Wb[p] + (((16 * w + li) * 256 + ks * 64 + hi * 16) ^ SWZ(li)));
      Y = __builtin_amdgcn_mfma_f32_16x16x32_bf16(fa, sfb[ks], Y, 0, 0, 0);
    }
#pragma unroll
    for (int r = 0; r < 4; r += 2) {  // Y^T -> LDS
      int j = 16 * w + hi * 4 + r;
      unsigned pk = (unsigned)f2b(Y[r]) | ((unsigned)f2b(Y[r + 1]) << 16);
      *(unsigned*)(Ytb + ((li * 128 + j * 2) ^ SWZ(li))) = pk;
    }
    LBAR();  // LDS-only: staged loads for c+1 stay in flight

    // O = diag(gamma) Q S + G Y
    f32x4 O = {0, 0, 0, 0};
#pragma unroll
    for (int ks = 0; ks < 4; ++ks) {
      s16x8 fa = *(const s16x8*)(Qb[p] + (((16 * w + li) * 256 + ks * 64 + hi * 16) ^ SWZ(li)));
      O = __builtin_amdgcn_mfma_f32_16x16x32_bf16(fa, sfb[ks], O, 0, 0, 0);
    }
    s16x8 yfb[2];
#pragma unroll
    for (int ks = 0; ks < 2; ++ks)
      yfb[ks] = *(const s16x8*)(Ytb + ((li * 128 + ks * 64 + hi * 16) ^ SWZ(li)));
#pragma unroll
    for (int r = 0; r < 4; ++r) O[r] *= gam[p][16 * w + hi * 4 + r];
#pragma unroll
    for (int ks = 0; ks < 2; ++ks) {
      s16x8 fa = *(const s16x8*)(Gb[p] + (((16 * w + li) * 128 + ks * 64 + hi * 16) ^ SWZ(li)));
      O = __builtin_amdgcn_mfma_f32_16x16x32_bf16(fa, yfb[ks], O, 0, 0, 0);
    }
#pragma unroll
    for (int r = 0; r < 4; ++r) {
      size_t oi = ((size_t)(b * T_LEN + c * 64 + 16 * w + hi * 4 + r) * H_N + h) * DV + s * 16 + li;
      out[oi] = O[r];
    }

    // S = gamma_end * S + Kd^T Y
    float ge = gam[p][63];
#pragma unroll
    for (int t = 0; t < 2; ++t) {
      f32x4 acc;
#pragma unroll
      for (int r = 0; r < 4; ++r) acc[r] = ge * S[t][r];
#pragma unroll
      for (int ks = 0; ks < 2; ++ks) {
        s16x8 fa = *(const s16x8*)(KDb[p] + ((((w + 4 * t) * 16 + li) * 128 + ks * 64 + hi * 16) ^ SWZ(li)));
        acc = __builtin_amdgcn_mfma_f32_16x16x32_bf16(fa, yfb[ks], acc, 0, 0, 0);
      }
#pragma unroll
      for (int r = 0; r < 4; ++r) S[t][r] = acc[r];
    }
    LBAR();     // all waves done reading Stb/Ytb
    WRITE_ST();
    __syncthreads();  // full: drains vmcnt (buf p^1 staged) + Stb visible
  }

  // final state
#pragma unroll
  for (int t = 0; t < 2; ++t)
#pragma unroll
    for (int r = 0; r < 4; ++r) {
      int d = (w + 4 * t) * 16 + hi * 4 + r;
      out[(size_t)(2 * T_LEN * H_N * DV) + ((size_t)bh * 128 + d) * 128 + s * 16 + li] = S[t][r];
    }
}

// ---------------- Fallback (round-5 kernel, used only if ws too small) ----
#define COLS 16
#define CHUNK 16
#define STEP_B 8192u
#define AB_B 64u
#define OSTRIDE (H_N * DV)
template <int CTRL>
__device__ __forceinline__ float dpp_add(float x) {
  int y = __builtin_amdgcn_update_dpp(0, __float_as_int(x), CTRL, 0xF, 0xF, true);
  return x + __int_as_float(y);
}
__device__ __forceinline__ float red16(float x) {
  x = dpp_add<0xB1>(x); x = dpp_add<0x4E>(x);
  x = dpp_add<0x124>(x); x = dpp_add<0x128>(x);
  return x;
}
extern "C" __global__ void __launch_bounds__(256, 1) gdn_fallback(
    const float* __restrict__ q, const float* __restrict__ k,
    const float* __restrict__ v, const float* __restrict__ al,
    const float* __restrict__ be, const float* __restrict__ S0,
    float* __restrict__ out) {
  __shared__ float kb[2][CHUNK * DK];
  __shared__ float qb[2][CHUNK * DK];
  __shared__ float vb[2][CHUNK * COLS];
  __shared__ float abuf[2][64];
  __shared__ float bbuf[2][64];
  const int bid = blockIdx.x;
  const int bh = bid & 31, g = bid >> 5;
  const int b = bh >> 4, h = bh & 15;
  const int tid = threadIdx.x;
  const int cl = tid >> 4, li = tid & 15, lane = tid & 63, wid = tid >> 6;
  const int col = g * COLS + cl, d0 = li * 8;
  const size_t bh_qk = ((size_t)b * T_LEN * H_N + h) * DK;
  const size_t bh_v = ((size_t)b * T_LEN * H_N + h) * DV;
  const size_t bh_ab = (size_t)b * T_LEN * H_N + h;
  const int fo0 = wid * 2048 + lane * 16, fo1 = fo0 + 1024;
  const char* kg0 = (const char*)(k + bh_qk) + (size_t)(fo0 >> 9) * STEP_B + (fo0 & 511);
  const char* kg1 = (const char*)(k + bh_qk) + (size_t)(fo1 >> 9) * STEP_B + (fo1 & 511);
  const char* qg0 = (const char*)(q + bh_qk) + (size_t)(fo0 >> 9) * STEP_B + (fo0 & 511);
  const char* qg1 = (const char*)(q + bh_qk) + (size_t)(fo1 >> 9) * STEP_B + (fo1 & 511);
  const int fv = lane * 16;
  const char* vg = (const char*)(v + bh_v + g * COLS) + (size_t)(fv >> 6) * STEP_B + (fv & 63);
  const int lcl = lane < 16 ? lane : 15;
  const char* ag = (const char*)(al + bh_ab) + (size_t)lcl * AB_B;
  const char* bg = (const char*)(be + bh_ab) + (size_t)lcl * AB_B;
#define STAGEF(CI, P) do { \
    const size_t off = (size_t)(CI) * (CHUNK * STEP_B); \
    const size_t offab = (size_t)(CI) * (CHUNK * AB_B); \
    GLDS16(kg0 + off, &kb[P][wid * 512]); GLDS16(kg1 + off, &kb[P][wid * 512 + 256]); \
    GLDS16(qg0 + off, &qb[P][wid * 512]); GLDS16(qg1 + off, &qb[P][wid * 512 + 256]); \
    if (wid == 0) GLDS16(vg + off, &vb[P][0]); \
    else if (wid == 1) GLDS4(ag + offab, &abuf[P][0]); \
    else if (wid == 2) GLDS4(bg + offab, &bbuf[P][0]); \
  } while (0)
  float sv[8];
  const float* s0p = S0 + ((size_t)(b * H_N + h) * DK + d0) * DV + col;
#pragma unroll
  for (int j = 0; j < 8; ++j) sv[j] = s0p[(size_t)j * DV];
  STAGEF(0, 0);
  __syncthreads();
  float* op = out + bh_v + col;
  for (int ci = 0; ci < T_LEN / CHUNK; ++ci) {
    const int p = ci & 1;
    if (ci + 1 < T_LEN / CHUNK) STAGEF(ci + 1, p ^ 1);
    const float* kc = kb[p]; const float* qc = qb[p]; const float* vc = vb[p];
    const float* ac = abuf[p]; const float* bc = bbuf[p];
#pragma unroll
    for (int j = 0; j < CHUNK; ++j) {
      f32x4 kA = *(const f32x4*)(kc + j * DK + d0);
      f32x4 kB = *(const f32x4*)(kc + j * DK + d0 + 4);
      f32x4 qA = *(const f32x4*)(qc + j * DK + d0);
      f32x4 qB = *(const f32x4*)(qc + j * DK + d0 + 4);
      float vv = vc[j * COLS + cl], aa = ac[j], bv = bc[j];
      float kk[8] = {kA[0], kA[1], kA[2], kA[3], kB[0], kB[1], kB[2], kB[3]};
      float qq[8] = {qA[0], qA[1], qA[2], qA[3], qB[0], qB[1], qB[2], qB[3]};
      float pk0 = kk[0] * sv[0], pk1 = kk[1] * sv[1];
      float pu0 = qq[0] * sv[0], pu1 = qq[1] * sv[1];
      float pg0 = kk[0] * qq[0], pg1 = kk[1] * qq[1];
#pragma unroll
      for (int m = 2; m < 8; m += 2) {
        pk0 = fmaf(kk[m], sv[m], pk0); pk1 = fmaf(kk[m + 1], sv[m + 1], pk1);
        pu0 = fmaf(qq[m], sv[m], pu0); pu1 = fmaf(qq[m + 1], sv[m + 1], pu1);
        pg0 = fmaf(kk[m], qq[m], pg0); pg1 = fmaf(kk[m + 1], qq[m + 1], pg1);
      }
      float pk = red16(pk0 + pk1), pu = red16(pu0 + pu1), pg = red16(pg0 + pg1);
      float tmp = fmaf(-(bv * aa), pk, bv * vv);
#pragma unroll
      for (int m = 0; m < 8; ++m) sv[m] = fmaf(aa, sv[m], kk[m] * tmp);
      if (li == 0) op[(size_t)(ci * CHUNK + j) * OSTRIDE] = fmaf(pg, tmp, aa * pu);
    }
    __syncthreads();
  }
  float* sf = out + (size_t)2 * T_LEN * H_N * DV + ((size_t)(b * H_N + h) * DK + d0) * DV + col;
#pragma unroll
  for (int j = 0; j < 8; ++j) sf[(size_t)j * DV] = sv[j];
}

extern "C" void kernel_launch(void* const* d_in, const int* in_sizes, int n_in,
                              void* d_out, int out_size, void* d_ws,
                              size_t ws_size, hipStream_t stream) {
  const float* q = (const float*)d_in[0];
  const float* k = (const float*)d_in[1];
  const float* v = (const float*)d_in[2];
  const float* al = (const float*)d_in[3];
  const float* be = (const float*)d_in[4];
  const float* S0 = (const float*)d_in[5];
  float* out = (float*)d_out;

  if (ws_size >= WS_NEED) {
    gdn_p1<<<dim3(2048), dim3(256), 0, stream>>>(q, k, v, al, be, (char*)d_ws);
    gdn_p2<<<dim3(256), dim3(256), 0, stream>>>(S0, out, (const char*)d_ws);
  } else {
    gdn_fallback<<<dim3(256), dim3(256), 0, stream>>>(q, k, v, al, be, S0, out);
  }
}